// Round 1
// baseline (282.418 us; speedup 1.0000x reference)
//
#include <hip/hip_runtime.h>

#define NPTS   16384
#define KN     16
#define CIN    64
#define COUT   64
#define KSIZ   16
#define BQ     8        // points per block

// Fold layer-1 weights: x = (rel - centers) is affine in rel, so
// h1 = relu(rel @ W1r + b1f) with W1r[d][n] = sum_s w1[d*16+s][n],
// b1f[n] = b1[n] - sum_{d,s} centers[d][s]*w1[d*16+s][n].
__global__ void fold_kernel(const float* __restrict__ w1,
                            const float* __restrict__ b1,
                            const float* __restrict__ centers,
                            float* __restrict__ ws) {
    int n = threadIdx.x;
    if (n < 32) {
        float s0 = 0.f, s1 = 0.f, s2 = 0.f;
        float bf = b1[n];
        for (int s = 0; s < KSIZ; ++s) {
            float a0 = w1[(0*KSIZ + s)*32 + n];
            float a1 = w1[(1*KSIZ + s)*32 + n];
            float a2 = w1[(2*KSIZ + s)*32 + n];
            s0 += a0; s1 += a1; s2 += a2;
            bf -= centers[0*KSIZ + s]*a0 + centers[1*KSIZ + s]*a1 + centers[2*KSIZ + s]*a2;
        }
        ws[0*32 + n] = s0;
        ws[1*32 + n] = s1;
        ws[2*32 + n] = s2;
        ws[96 + n]   = bf;
    }
}

__global__ __launch_bounds__(256, 3)
void ptconv_kernel(const float* __restrict__ features,     // [B][N][64]
                   const float* __restrict__ input_pts,    // [B][N][3]
                   const float* __restrict__ output_pts,   // [B][N][3]
                   const float* __restrict__ weight,       // [64][16][64]
                   const float* __restrict__ bias,         // [64]
                   const float* __restrict__ w2,           // [32][16]
                   const float* __restrict__ b2,           // [16]
                   const float* __restrict__ w3,           // [16][16]
                   const float* __restrict__ b3,           // [16]
                   const int*   __restrict__ indices,      // [B][N][16]
                   const float* __restrict__ folded,       // ws: W1r[3][32], b1f[32]
                   float* __restrict__ out) {              // [B][N][64]
    __shared__ float s_w1r[3][32];
    __shared__ float s_b1f[32];
    __shared__ float s_w2t[16][32];          // transposed: [n2][i]
    __shared__ float s_b2[16];
    __shared__ float s_w3t[16][16];          // transposed: [n3][i]
    __shared__ float s_b3[16];
    __shared__ int   s_idx[BQ][KN];
    __shared__ float s_d[BQ][KN][KSIZ];      // d-tensor; aliased as s_red later
    __shared__ float s_agg[BQ][CIN*20];      // agg[p][c*20+j], stride 20 pad

    const int t    = threadIdx.x;
    const int lane = t & 63;
    const int wave = t >> 6;
    const int m0   = blockIdx.x * BQ;

    // ---- stage MLP params into LDS ----
    if (t < 96)       s_w1r[t>>5][t&31] = folded[t];
    else if (t < 128) s_b1f[t-96]       = folded[t];
    for (int e = t; e < 512; e += 256) { int i = e >> 4, n2 = e & 15; s_w2t[n2][i] = w2[e]; }
    if (t < 256)      { int i = t >> 4, n3 = t & 15; s_w3t[n3][i] = w3[t]; }
    if (t < 16)             s_b2[t]    = b2[t];
    else if (t < 32)        s_b3[t-16] = b3[t-16];
    __syncthreads();

    // ---- phase 1: position MLP, one thread per (point, neighbor) ----
    if (t < BQ*KN) {
        const int p  = t >> 4, k = t & 15;
        const int m  = m0 + p;
        const int bb = m >> 14;              // / NPTS
        const int nn = m & (NPTS-1);
        const int idxv = indices[(bb*NPTS + nn)*KN + k];
        s_idx[p][k] = idxv;
        const float* ip = input_pts  + (size_t)(bb*NPTS + idxv)*3;
        const float* op = output_pts + (size_t)(bb*NPTS + nn)*3;
        const float r0 = ip[0]-op[0], r1 = ip[1]-op[1], r2 = ip[2]-op[2];
        float h1[32];
        #pragma unroll
        for (int n1 = 0; n1 < 32; ++n1) {
            float a = s_b1f[n1];
            a = fmaf(r0, s_w1r[0][n1], a);
            a = fmaf(r1, s_w1r[1][n1], a);
            a = fmaf(r2, s_w1r[2][n1], a);
            h1[n1] = fmaxf(a, 0.f);
        }
        float h2[16];
        #pragma unroll
        for (int n2 = 0; n2 < 16; ++n2) {
            float a = s_b2[n2];
            #pragma unroll
            for (int i = 0; i < 32; ++i) a = fmaf(h1[i], s_w2t[n2][i], a);
            h2[n2] = fmaxf(a, 0.f);
        }
        #pragma unroll
        for (int n3 = 0; n3 < 16; ++n3) {
            float a = s_b3[n3];
            #pragma unroll
            for (int i = 0; i < 16; ++i) a = fmaf(h2[i], s_w3t[n3][i], a);
            s_d[p][k][n3] = fmaxf(a, 0.f);
        }
    }
    __syncthreads();

    // ---- phase 2: agg[p][c][j] = sum_k feat[idx[k]][c] * d[k][j]  (lane = c) ----
    #pragma unroll
    for (int pp = 0; pp < 2; ++pp) {
        const int p  = wave*2 + pp;
        const int m  = m0 + p;
        const int bb = m >> 14;
        const float* fb = features + (size_t)bb*NPTS*CIN;
        float acc[16];
        #pragma unroll
        for (int j = 0; j < 16; ++j) acc[j] = 0.f;
        #pragma unroll
        for (int k = 0; k < KN; ++k) {
            const float f = fb[(size_t)s_idx[p][k]*CIN + lane];
            const float4* dv = reinterpret_cast<const float4*>(&s_d[p][k][0]);
            const float4 d0 = dv[0], d1 = dv[1], d2 = dv[2], d3 = dv[3];
            acc[0]  = fmaf(f, d0.x, acc[0]);  acc[1]  = fmaf(f, d0.y, acc[1]);
            acc[2]  = fmaf(f, d0.z, acc[2]);  acc[3]  = fmaf(f, d0.w, acc[3]);
            acc[4]  = fmaf(f, d1.x, acc[4]);  acc[5]  = fmaf(f, d1.y, acc[5]);
            acc[6]  = fmaf(f, d1.z, acc[6]);  acc[7]  = fmaf(f, d1.w, acc[7]);
            acc[8]  = fmaf(f, d2.x, acc[8]);  acc[9]  = fmaf(f, d2.y, acc[9]);
            acc[10] = fmaf(f, d2.z, acc[10]); acc[11] = fmaf(f, d2.w, acc[11]);
            acc[12] = fmaf(f, d3.x, acc[12]); acc[13] = fmaf(f, d3.y, acc[13]);
            acc[14] = fmaf(f, d3.z, acc[14]); acc[15] = fmaf(f, d3.w, acc[15]);
        }
        float* ap = &s_agg[p][lane*20];
        *reinterpret_cast<float4*>(ap+0)  = make_float4(acc[0],  acc[1],  acc[2],  acc[3]);
        *reinterpret_cast<float4*>(ap+4)  = make_float4(acc[4],  acc[5],  acc[6],  acc[7]);
        *reinterpret_cast<float4*>(ap+8)  = make_float4(acc[8],  acc[9],  acc[10], acc[11]);
        *reinterpret_cast<float4*>(ap+12) = make_float4(acc[12], acc[13], acc[14], acc[15]);
    }
    __syncthreads();

    // ---- phase 3: out[p][o] partials; wave w covers cj in [w*256, w*256+256) ----
    float po[BQ];
    #pragma unroll
    for (int p = 0; p < BQ; ++p) po[p] = 0.f;
    const int cjb = wave * 256;
    #pragma unroll 4
    for (int i4 = 0; i4 < 64; ++i4) {
        const int cj = cjb + i4*4;
        const float w0v = weight[(size_t)(cj+0)*COUT + lane];
        const float w1v = weight[(size_t)(cj+1)*COUT + lane];
        const float w2v = weight[(size_t)(cj+2)*COUT + lane];
        const float w3v = weight[(size_t)(cj+3)*COUT + lane];
        const int c  = cj >> 4;
        const int j0 = cj & 15;
        #pragma unroll
        for (int p = 0; p < BQ; ++p) {
            const float4 a = *reinterpret_cast<const float4*>(&s_agg[p][c*20 + j0]);
            po[p] = fmaf(a.x, w0v, po[p]);
            po[p] = fmaf(a.y, w1v, po[p]);
            po[p] = fmaf(a.z, w2v, po[p]);
            po[p] = fmaf(a.w, w3v, po[p]);
        }
    }

    // ---- cross-wave reduction through LDS (reuse s_d space) ----
    float* s_red = &s_d[0][0][0];            // 4*BQ*64 = 2048 floats = s_d size
    #pragma unroll
    for (int p = 0; p < BQ; ++p) s_red[(wave*BQ + p)*64 + lane] = po[p];
    __syncthreads();
    for (int e = t; e < BQ*COUT; e += 256) {
        const int p = e >> 6, o = e & 63;
        const float v = s_red[(0*BQ+p)*64+o] + s_red[(1*BQ+p)*64+o]
                      + s_red[(2*BQ+p)*64+o] + s_red[(3*BQ+p)*64+o];
        out[(size_t)(m0 + p)*COUT + o] = v*(1.0f/16.0f) + bias[o];
    }
}

extern "C" void kernel_launch(void* const* d_in, const int* in_sizes, int n_in,
                              void* d_out, int out_size, void* d_ws, size_t ws_size,
                              hipStream_t stream) {
    const float* features   = (const float*)d_in[0];
    const float* input_pts  = (const float*)d_in[1];
    const float* output_pts = (const float*)d_in[2];
    const float* weight     = (const float*)d_in[3];
    const float* bias       = (const float*)d_in[4];
    const float* centers    = (const float*)d_in[5];
    const float* w1         = (const float*)d_in[6];
    const float* b1         = (const float*)d_in[7];
    const float* w2         = (const float*)d_in[8];
    const float* b2         = (const float*)d_in[9];
    const float* w3         = (const float*)d_in[10];
    const float* b3         = (const float*)d_in[11];
    const int*   indices    = (const int*)d_in[12];
    float* out = (float*)d_out;
    float* ws  = (float*)d_ws;

    fold_kernel<<<1, 64, 0, stream>>>(w1, b1, centers, ws);

    const int total_pts = 4 * NPTS;          // B*N = 65536
    ptconv_kernel<<<total_pts / BQ, 256, 0, stream>>>(
        features, input_pts, output_pts, weight, bias,
        w2, b2, w3, b3, indices, ws, out);
}

// Round 2
// 109.333 us; speedup vs baseline: 2.5831x; 2.5831x over previous
//
#include <hip/hip_runtime.h>

#define NPTS 16384
#define KN   16
#define CIN  64
#define COUT 64
#define KSIZ 16
#define PTS  16      // points per block

typedef short bf16x8 __attribute__((ext_vector_type(8)));
typedef float f32x4  __attribute__((ext_vector_type(4)));

__device__ __host__ inline unsigned short f2bf(float f) {
    union { float f; unsigned u; } v; v.f = f;
    unsigned r = v.u + 0x7fffu + ((v.u >> 16) & 1u);   // RNE
    return (unsigned short)(r >> 16);
}

// Fold layer-1: x = (rel - centers) is affine in rel.
__global__ void fold_kernel(const float* __restrict__ w1,
                            const float* __restrict__ b1,
                            const float* __restrict__ centers,
                            float* __restrict__ ws) {
    int n = threadIdx.x;
    if (n < 32) {
        float s0 = 0.f, s1 = 0.f, s2 = 0.f, bf = b1[n];
        for (int s = 0; s < KSIZ; ++s) {
            float a0 = w1[(0*KSIZ + s)*32 + n];
            float a1 = w1[(1*KSIZ + s)*32 + n];
            float a2 = w1[(2*KSIZ + s)*32 + n];
            s0 += a0; s1 += a1; s2 += a2;
            bf -= centers[0*KSIZ+s]*a0 + centers[1*KSIZ+s]*a1 + centers[2*KSIZ+s]*a2;
        }
        ws[0*32+n] = s0; ws[1*32+n] = s1; ws[2*32+n] = s2; ws[96+n] = bf;
    }
}

// Pre-pack W[c][j][o] (fp32) into bf16 MFMA B-fragment order.
// Slot s (0..1023) <-> (c,j): s = (j>>1)*128 + c*2 + (j&1).
// Fragment: K-step kk, n-tile nt, lane l, elem e -> slot s = kk*32 + (l>>4)*8 + e,
//           n = nt*16 + (l&15). (Same (lane,e)->s map used by the consumer, so the
//           true HW K-order is irrelevant — contraction is permutation-invariant.)
__global__ void wfrag_kernel(const float* __restrict__ weight,
                             uint4* __restrict__ wf) {
    const int b  = blockIdx.x;          // 128 blocks of 64 threads
    const int kk = b >> 2, nt = b & 3;
    const int l  = threadIdx.x, li = l & 15, g = l >> 4;
    unsigned short u[8];
    #pragma unroll
    for (int e = 0; e < 8; ++e) {
        int s = kk*32 + g*8 + e;
        int j = 2*(s >> 7) + (s & 1);
        int c = (s >> 1) & 63;
        u[e] = f2bf(weight[(c*16 + j)*64 + nt*16 + li]);
    }
    uint4 v;
    v.x = u[0] | ((unsigned)u[1] << 16);
    v.y = u[2] | ((unsigned)u[3] << 16);
    v.z = u[4] | ((unsigned)u[5] << 16);
    v.w = u[6] | ((unsigned)u[7] << 16);
    wf[(kk*4 + nt)*64 + l] = v;
}

__global__ __launch_bounds__(256, 3)
void ptconv_kernel(const float* __restrict__ features,
                   const float* __restrict__ input_pts,
                   const float* __restrict__ output_pts,
                   const float* __restrict__ bias,
                   const float* __restrict__ w2,
                   const float* __restrict__ b2,
                   const float* __restrict__ w3,
                   const float* __restrict__ b3,
                   const int*   __restrict__ indices,
                   const float* __restrict__ folded,     // ws[0:128]
                   const uint4* __restrict__ wf,         // pre-packed W fragments
                   float* __restrict__ out) {
    __shared__ float s_w1r[3][32];
    __shared__ float s_b1f[32];
    __shared__ float s_w2t[16][32];
    __shared__ float s_b2[16];
    __shared__ float s_w3t[16][16];
    __shared__ float s_b3[16];
    __shared__ int   s_idx[PTS][KN];
    __shared__ unsigned short s_dT[PTS*16*24];   // [p][j][24] bf16, row pad->16B align
    __shared__ unsigned short s_agg[PTS*1032];   // [m][1024 slots], row 2064 B

    const int t    = threadIdx.x;
    const int l    = t & 63;
    const int wave = t >> 6;
    const int li   = l & 15;
    const int g    = l >> 4;
    const int m0   = blockIdx.x * PTS;
    const int bbk  = m0 >> 14;                   // whole block same batch

    // ---- stage MLP params ----
    if (t < 96)       s_w1r[t>>5][t&31] = folded[t];
    else if (t < 128) s_b1f[t-96]       = folded[t];
    for (int e = t; e < 512; e += 256) { int i = e >> 4, n2 = e & 15; s_w2t[n2][i] = w2[e]; }
    { int i = t >> 4, n3 = t & 15; s_w3t[n3][i] = w3[t]; }
    if (t < 16)       s_b2[t]    = b2[t];
    else if (t < 32)  s_b3[t-16] = b3[t-16];

    // ---- phase 1 prologue: one (point, neighbor) pair per thread ----
    const int p1 = t >> 4, k1 = t & 15;
    const int m  = m0 + p1;
    const int nn = m & (NPTS-1);
    const int idxv = indices[(bbk*NPTS + nn)*KN + k1];
    s_idx[p1][k1] = idxv;
    const float* ip = input_pts  + (size_t)(bbk*NPTS + idxv)*3;
    const float* op = output_pts + (size_t)(bbk*NPTS + nn)*3;
    const float r0 = ip[0]-op[0], r1 = ip[1]-op[1], r2 = ip[2]-op[2];
    __syncthreads();

    // ---- phase 1: position MLP (fp32), write d^T as bf16 ----
    {
        float h1[32];
        #pragma unroll
        for (int n1 = 0; n1 < 32; ++n1) {
            float a = s_b1f[n1];
            a = fmaf(r0, s_w1r[0][n1], a);
            a = fmaf(r1, s_w1r[1][n1], a);
            a = fmaf(r2, s_w1r[2][n1], a);
            h1[n1] = fmaxf(a, 0.f);
        }
        float h2[16];
        #pragma unroll
        for (int n2 = 0; n2 < 16; ++n2) {
            float a = s_b2[n2];
            #pragma unroll
            for (int i = 0; i < 32; ++i) a = fmaf(h1[i], s_w2t[n2][i], a);
            h2[n2] = fmaxf(a, 0.f);
        }
        #pragma unroll
        for (int j = 0; j < 16; ++j) {
            float a = s_b3[j];
            #pragma unroll
            for (int i = 0; i < 16; ++i) a = fmaf(h2[i], s_w3t[j][i], a);
            s_dT[(p1*16 + j)*24 + k1] = f2bf(fmaxf(a, 0.f));
        }
    }
    __syncthreads();

    // ---- phase 2: per point, agg^T[j][c] = sum_k d[k][j] * feat[k][c] via MFMA ----
    // A[m=j][k] = d[k][j] (k<16 real, k>=16 zero-pad), B[k][n=c] = feat[idx[k]][c].
    const float* fb = features + (size_t)bbk*NPTS*CIN;
    for (int pp = 0; pp < 4; ++pp) {
        const int p2 = wave*4 + pp;
        union { uint4 u; bf16x8 v; } A; A.u = make_uint4(0,0,0,0);
        int rows[8];
        if (g < 2) {
            A.u = *(const uint4*)&s_dT[(p2*16 + li)*24 + g*8];
            #pragma unroll
            for (int e = 0; e < 8; ++e) rows[e] = s_idx[p2][g*8 + e];
        }
        #pragma unroll
        for (int ct = 0; ct < 4; ++ct) {
            const int c = ct*16 + li;
            union { uint4 u; bf16x8 v; } Bf; Bf.u = make_uint4(0,0,0,0);
            if (g < 2) {
                unsigned short ub[8];
                #pragma unroll
                for (int e = 0; e < 8; ++e) ub[e] = f2bf(fb[(size_t)rows[e]*CIN + c]);
                Bf.u.x = ub[0] | ((unsigned)ub[1] << 16);
                Bf.u.y = ub[2] | ((unsigned)ub[3] << 16);
                Bf.u.z = ub[4] | ((unsigned)ub[5] << 16);
                Bf.u.w = ub[6] | ((unsigned)ub[7] << 16);
            }
            f32x4 acc = {0.f, 0.f, 0.f, 0.f};
            acc = __builtin_amdgcn_mfma_f32_16x16x32_bf16(A.v, Bf.v, acc, 0, 0, 0);
            // D: row j = g*4 + r, col = c. Store to slot s=(j>>1)*128 + c*2 + (j&1).
            unsigned w01 = f2bf(acc[0]) | ((unsigned)f2bf(acc[1]) << 16);  // j=4g,4g+1
            unsigned w23 = f2bf(acc[2]) | ((unsigned)f2bf(acc[3]) << 16);  // j=4g+2,4g+3
            *(unsigned*)&s_agg[p2*1032 + (2*g+0)*128 + c*2] = w01;
            *(unsigned*)&s_agg[p2*1032 + (2*g+1)*128 + c*2] = w23;
        }
    }
    __syncthreads();

    // ---- phase 3: out[16 pts][64] = AGG[16][1024] x W[1024][64], n-tile = wave ----
    f32x4 acc = {0.f, 0.f, 0.f, 0.f};
    #pragma unroll 4
    for (int kk = 0; kk < 32; ++kk) {
        union { uint4 u; bf16x8 v; } Af, Bf;
        Bf.u = wf[(kk*4 + wave)*64 + l];                         // 16B coalesced (L2)
        Af.u = *(const uint4*)&s_agg[li*1032 + kk*32 + g*8];     // row m=li, slots kk*32+g*8..+7
        acc = __builtin_amdgcn_mfma_f32_16x16x32_bf16(Af.v, Bf.v, acc, 0, 0, 0);
    }
    const float bo = bias[wave*16 + li];
    #pragma unroll
    for (int r = 0; r < 4; ++r) {
        const int mr = g*4 + r;
        out[(size_t)(m0 + mr)*COUT + wave*16 + li] = acc[r]*0.0625f + bo;
    }
}

extern "C" void kernel_launch(void* const* d_in, const int* in_sizes, int n_in,
                              void* d_out, int out_size, void* d_ws, size_t ws_size,
                              hipStream_t stream) {
    const float* features   = (const float*)d_in[0];
    const float* input_pts  = (const float*)d_in[1];
    const float* output_pts = (const float*)d_in[2];
    const float* weight     = (const float*)d_in[3];
    const float* bias       = (const float*)d_in[4];
    const float* centers    = (const float*)d_in[5];
    const float* w1         = (const float*)d_in[6];
    const float* b1         = (const float*)d_in[7];
    const float* w2         = (const float*)d_in[8];
    const float* b2         = (const float*)d_in[9];
    const float* w3         = (const float*)d_in[10];
    const float* b3         = (const float*)d_in[11];
    const int*   indices    = (const int*)d_in[12];
    float* out = (float*)d_out;
    float* ws  = (float*)d_ws;
    uint4* wf  = (uint4*)((char*)d_ws + 512);   // 128 KB of bf16 W fragments

    fold_kernel <<<1, 64, 0, stream>>>(w1, b1, centers, ws);
    wfrag_kernel<<<128, 64, 0, stream>>>(weight, wf);

    const int total_pts = 4 * NPTS;             // 65536
    ptconv_kernel<<<total_pts / PTS, 256, 0, stream>>>(
        features, input_pts, output_pts, bias,
        w2, b2, w3, b3, indices, ws, wf, out);
}

// Round 4
// 64.549 us; speedup vs baseline: 4.3752x; 1.6938x over previous
//
#include <hip/hip_runtime.h>

#define NPTS 16384
#define KN   16
#define CIN  64
#define COUT 64
#define KSIZ 16
#define PTS  16      // points per block

typedef _Float16 h4v    __attribute__((ext_vector_type(4)));
typedef _Float16 h8v    __attribute__((ext_vector_type(8)));
typedef __fp16   fp16x2 __attribute__((ext_vector_type(2)));
typedef float    f32x4  __attribute__((ext_vector_type(4)));

union H2U { fp16x2 h; unsigned u; };

// Fold layer-1: x = (rel - centers) is affine in rel.
__global__ void fold_kernel(const float* __restrict__ w1,
                            const float* __restrict__ b1,
                            const float* __restrict__ centers,
                            float* __restrict__ ws) {
    int n = threadIdx.x;
    if (n < 32) {
        float s0 = 0.f, s1 = 0.f, s2 = 0.f, bf = b1[n];
        for (int s = 0; s < KSIZ; ++s) {
            float a0 = w1[(0*KSIZ + s)*32 + n];
            float a1 = w1[(1*KSIZ + s)*32 + n];
            float a2 = w1[(2*KSIZ + s)*32 + n];
            s0 += a0; s1 += a1; s2 += a2;
            bf -= centers[0*KSIZ+s]*a0 + centers[1*KSIZ+s]*a1 + centers[2*KSIZ+s]*a2;
        }
        ws[0*32+n] = s0; ws[1*32+n] = s1; ws[2*32+n] = s2; ws[96+n] = bf;
    }
}

// Pre-pack W[c][j][o] (fp32) into f16 MFMA B-fragment order.
// Slot s (0..1023) <-> (c,j): s = (j>>1)*128 + c*2 + (j&1).
// Fragment: K-step kk, n-tile nt, lane l, elem e -> slot s = kk*32 + (l>>4)*8 + e,
//           n = nt*16 + (l&15). Consumer uses the identical map -> k-permutation-invariant.
__global__ void wfrag_kernel(const float* __restrict__ weight,
                             uint4* __restrict__ wf) {
    const int b  = blockIdx.x;          // 128 blocks of 64 threads
    const int kk = b >> 2, nt = b & 3;
    const int l  = threadIdx.x, li = l & 15, g = l >> 4;
    unsigned short u[8];
    #pragma unroll
    for (int e = 0; e < 8; ++e) {
        int s = kk*32 + g*8 + e;
        int j = 2*(s >> 7) + (s & 1);
        int c = (s >> 1) & 63;
        union { _Float16 h; unsigned short s16; } cv;
        cv.h = (_Float16)weight[(c*16 + j)*64 + nt*16 + li];
        u[e] = cv.s16;
    }
    uint4 v;
    v.x = u[0] | ((unsigned)u[1] << 16);
    v.y = u[2] | ((unsigned)u[3] << 16);
    v.z = u[4] | ((unsigned)u[5] << 16);
    v.w = u[6] | ((unsigned)u[7] << 16);
    wf[(kk*4 + nt)*64 + l] = v;
}

__global__ __launch_bounds__(256, 3)
void ptconv_kernel(const float* __restrict__ features,
                   const float* __restrict__ input_pts,
                   const float* __restrict__ output_pts,
                   const float* __restrict__ bias,
                   const float* __restrict__ w2,
                   const float* __restrict__ b2,
                   const float* __restrict__ w3,
                   const float* __restrict__ b3,
                   const int*   __restrict__ indices,
                   const float* __restrict__ folded,     // ws[0:128]
                   const uint4* __restrict__ wf,         // pre-packed W fragments (f16)
                   float* __restrict__ out) {
    // LDS map (bytes):
    //   [0, 33024)      s_agg [16 pts][2064]   (f16 slots, 516 dwords/row)
    //                   aliased by s_h1 [256 rows][80] during layers 1-2
    //   [33024, 35072)  s_h2w [4 waves][512]   wave-private 16x16 f16 tile
    //   [35072, 43264)  s_dT  [16 tiles][512]  d as [j][k] f16
    //   [43264, 44288)  s_idx [256] int
    //   [44288, 44800)  s_par [128] float (W1r | b1f)
    __shared__ __align__(16) char smem[44800];
    char*  s_agg = smem;
    char*  s_h1  = smem;
    char*  s_h2w = smem + 33024;
    char*  s_dT  = smem + 35072;
    int*   s_idx = (int*)(smem + 43264);
    float* s_par = (float*)(smem + 44288);

    const int t    = threadIdx.x;
    const int l    = t & 63;
    const int wave = t >> 6;
    const int li   = l & 15;
    const int g    = l >> 4;
    const int m0   = blockIdx.x * PTS;
    const int bbk  = m0 >> 14;

    if (t < 128) s_par[t] = folded[t];

    // per-thread neighbor (point p1, neighbor k1)
    const int p1 = t >> 4, k1 = t & 15;
    const int nn = (m0 + p1) & (NPTS-1);
    const int idxv = indices[(bbk*NPTS + nn)*KN + k1];
    s_idx[p1*16 + k1] = idxv;
    const float* ip = input_pts  + (size_t)(bbk*NPTS + idxv)*3;
    const float* op = output_pts + (size_t)(bbk*NPTS + nn)*3;
    const float r0 = ip[0]-op[0], r1 = ip[1]-op[1], r2 = ip[2]-op[2];

    // weight fragments in registers (loaded once)
    h8v w2f; h4v w3f;
    #pragma unroll
    for (int e = 0; e < 8; ++e) w2f[e] = (_Float16)w2[(8*g+e)*16 + li];
    #pragma unroll
    for (int e = 0; e < 4; ++e) w3f[e] = (_Float16)w3[(4*g+e)*16 + li];
    const float b2v   = b2[li];
    const float b3v   = b3[li];
    const float biasO = bias[wave*16 + li];

    __syncthreads();                              // params staged

    // ---- layer 1 (VALU, affine-folded): h1 f16 -> s_h1[row t] ----
    {
        const float4* W0 = (const float4*)(s_par + 0);
        const float4* W1 = (const float4*)(s_par + 32);
        const float4* W2 = (const float4*)(s_par + 64);
        const float4* BF = (const float4*)(s_par + 96);
        unsigned o16[16];
        #pragma unroll
        for (int q = 0; q < 8; ++q) {
            const float4 bq = BF[q], a0 = W0[q], a1 = W1[q], a2 = W2[q];
            float v0 = fmaxf(fmaf(r2, a2.x, fmaf(r1, a1.x, fmaf(r0, a0.x, bq.x))), 0.f);
            float v1 = fmaxf(fmaf(r2, a2.y, fmaf(r1, a1.y, fmaf(r0, a0.y, bq.y))), 0.f);
            float v2 = fmaxf(fmaf(r2, a2.z, fmaf(r1, a1.z, fmaf(r0, a0.z, bq.z))), 0.f);
            float v3 = fmaxf(fmaf(r2, a2.w, fmaf(r1, a1.w, fmaf(r0, a0.w, bq.w))), 0.f);
            H2U u0, u1;
            u0.h = __builtin_amdgcn_cvt_pkrtz(v0, v1);
            u1.h = __builtin_amdgcn_cvt_pkrtz(v2, v3);
            o16[2*q]   = u0.u;
            o16[2*q+1] = u1.u;
        }
        uint4* dst = (uint4*)(s_h1 + t*80);
        dst[0] = make_uint4(o16[0],  o16[1],  o16[2],  o16[3]);
        dst[1] = make_uint4(o16[4],  o16[5],  o16[6],  o16[7]);
        dst[2] = make_uint4(o16[8],  o16[9],  o16[10], o16[11]);
        dst[3] = make_uint4(o16[12], o16[13], o16[14], o16[15]);
    }
    // no barrier: each wave reads only rows written by its own threads

    // ---- layers 2+3 on MFMA, per point-tile mt (wave-private pipeline) ----
    #pragma unroll
    for (int pp = 0; pp < 4; ++pp) {
        const int mt = wave*4 + pp;
        // layer 2: [16 nbr,32] @ w2[32,16], K=32, A k=8g+e
        h8v A2 = *(const h8v*)(s_h1 + (mt*16 + li)*80 + g*16);
        f32x4 acc2 = {b2v, b2v, b2v, b2v};
        acc2 = __builtin_amdgcn_mfma_f32_16x16x32_f16(A2, w2f, acc2, 0, 0, 0);
        // relu -> f16, scatter to wave-private s_h2w [m][k]: rows 4g+r, col li
        #pragma unroll
        for (int r = 0; r < 4; ++r) {
            *(_Float16*)(s_h2w + wave*512 + (4*g + r)*32 + li*2) =
                (_Float16)fmaxf(acc2[r], 0.f);
        }
        // layer 3: [16 nbr,16] @ w3[16,16], K=16, A k=4g+e (b64 row read)
        h4v A3 = *(const h4v*)(s_h2w + wave*512 + li*32 + g*8);
        f32x4 acc3 = {b3v, b3v, b3v, b3v};
        acc3 = __builtin_amdgcn_mfma_f32_16x16x16f16(A3, w3f, acc3, 0, 0, 0);
        // relu -> f16 pairs -> s_dT[mt] as [j][k]: row j=li, cols k=4g..4g+3 (b64)
        H2U q01, q23;
        q01.h = __builtin_amdgcn_cvt_pkrtz(fmaxf(acc3[0],0.f), fmaxf(acc3[1],0.f));
        q23.h = __builtin_amdgcn_cvt_pkrtz(fmaxf(acc3[2],0.f), fmaxf(acc3[3],0.f));
        *(uint2*)(s_dT + mt*512 + li*32 + g*8) = make_uint2(q01.u, q23.u);
    }
    __syncthreads();   // s_h1 dead everywhere -> s_agg region may be written

    // ---- phase 2: agg^T[j][c] = sum_k d[k][j] * feat[idx[k]][c], K=16 exact ----
    const float* fb = features + (size_t)bbk*NPTS*CIN;
    #pragma unroll
    for (int pp = 0; pp < 4; ++pp) {
        const int p2 = wave*4 + pp;
        const int4 id4 = *(const int4*)(s_idx + p2*16 + g*4);
        const h4v  Ad  = *(const h4v*)(s_dT + p2*512 + li*32 + g*8);
        const float* q0 = fb + (size_t)id4.x*64 + li;
        const float* q1 = fb + (size_t)id4.y*64 + li;
        const float* q2 = fb + (size_t)id4.z*64 + li;
        const float* q3 = fb + (size_t)id4.w*64 + li;
        float f0[4], f1[4], f2[4], f3[4];
        #pragma unroll
        for (int ct = 0; ct < 4; ++ct) {
            f0[ct] = q0[ct*16]; f1[ct] = q1[ct*16];
            f2[ct] = q2[ct*16]; f3[ct] = q3[ct*16];
        }
        unsigned* aggp = (unsigned*)(s_agg) + p2*516;
        #pragma unroll
        for (int ct = 0; ct < 4; ++ct) {
            union { h4v v; fp16x2 p[2]; } B;
            B.p[0] = __builtin_amdgcn_cvt_pkrtz(f0[ct], f1[ct]);
            B.p[1] = __builtin_amdgcn_cvt_pkrtz(f2[ct], f3[ct]);
            f32x4 acc = {0.f, 0.f, 0.f, 0.f};
            acc = __builtin_amdgcn_mfma_f32_16x16x16f16(Ad, B.v, acc, 0, 0, 0);
            // D rows j=4g+r, col c=ct*16+li -> slot dwords jp*64 + c (jp=j>>1)
            H2U d01, d23;
            d01.h = __builtin_amdgcn_cvt_pkrtz(acc[0], acc[1]);
            d23.h = __builtin_amdgcn_cvt_pkrtz(acc[2], acc[3]);
            aggp[(2*g + 0)*64 + ct*16 + li] = d01.u;
            aggp[(2*g + 1)*64 + ct*16 + li] = d23.u;
        }
    }
    __syncthreads();

    // ---- phase 3: out[16 pts][64] = AGG[16][1024] x W[1024][64], n-tile = wave ----
    f32x4 acc = {0.f, 0.f, 0.f, 0.f};
    #pragma unroll 4
    for (int kk = 0; kk < 32; ++kk) {
        h8v Bf = *(const h8v*)&wf[(kk*4 + wave)*64 + l];          // 16B coalesced (L2)
        h8v Af = *(const h8v*)(s_agg + li*2064 + kk*64 + g*16);   // row m=li
        acc = __builtin_amdgcn_mfma_f32_16x16x32_f16(Af, Bf, acc, 0, 0, 0);
    }
    #pragma unroll
    for (int r = 0; r < 4; ++r) {
        const int mr = g*4 + r;
        out[(size_t)(m0 + mr)*COUT + wave*16 + li] = acc[r]*0.0625f + biasO;
    }
}

extern "C" void kernel_launch(void* const* d_in, const int* in_sizes, int n_in,
                              void* d_out, int out_size, void* d_ws, size_t ws_size,
                              hipStream_t stream) {
    const float* features   = (const float*)d_in[0];
    const float* input_pts  = (const float*)d_in[1];
    const float* output_pts = (const float*)d_in[2];
    const float* weight     = (const float*)d_in[3];
    const float* bias       = (const float*)d_in[4];
    const float* centers    = (const float*)d_in[5];
    const float* w1         = (const float*)d_in[6];
    const float* b1         = (const float*)d_in[7];
    const float* w2         = (const float*)d_in[8];
    const float* b2         = (const float*)d_in[9];
    const float* w3         = (const float*)d_in[10];
    const float* b3         = (const float*)d_in[11];
    const int*   indices    = (const int*)d_in[12];
    float* out = (float*)d_out;
    float* ws  = (float*)d_ws;
    uint4* wf  = (uint4*)((char*)d_ws + 512);   // 128 KB of f16 W fragments

    fold_kernel <<<1, 64, 0, stream>>>(w1, b1, centers, ws);
    wfrag_kernel<<<128, 64, 0, stream>>>(weight, wf);

    const int total_pts = 4 * NPTS;             // 65536
    ptconv_kernel<<<total_pts / PTS, 256, 0, stream>>>(
        features, input_pts, output_pts, bias,
        w2, b2, w3, b3, indices, ws, wf, out);
}

// Round 5
// 52.292 us; speedup vs baseline: 5.4008x; 1.2344x over previous
//
#include <hip/hip_runtime.h>

#define NPTS 16384
#define KN   16
#define CIN  64
#define COUT 64
#define KSIZ 16
#define PTS  16      // points per block

typedef _Float16 h4v    __attribute__((ext_vector_type(4)));
typedef _Float16 h8v    __attribute__((ext_vector_type(8)));
typedef __fp16   fp16x2 __attribute__((ext_vector_type(2)));
typedef float    f32x4  __attribute__((ext_vector_type(4)));

union H2U { fp16x2 h; unsigned u; };
union H4U { h4v v; fp16x2 p[2]; uint2 u2; };
union H8U { h8v v; fp16x2 p[4]; uint4 u4; };

// prep: blocks 0..127 pack W into f16 B-fragment order; block 128 folds layer-1.
// Slot s (0..1023) <-> (j,c): j = s>>6, c = s&63  (byte 2s in a [j][c] f16 row).
// Fragment: K-step kk, n-tile nt, lane l, elem e -> s = kk*32 + (l>>4)*8 + e,
//           o = nt*16 + (l&15). Consumer uses identical maps on A and B.
__global__ void prep_kernel(const float* __restrict__ weight,
                            const float* __restrict__ w1,
                            const float* __restrict__ b1,
                            const float* __restrict__ centers,
                            float* __restrict__ ws,
                            uint4* __restrict__ wf) {
    const int b = blockIdx.x;
    const int tid = threadIdx.x;
    if (b == 128) {                     // fold layer-1 (affine in rel)
        int n = tid;
        if (n < 32) {
            float s0 = 0.f, s1 = 0.f, s2 = 0.f, bf = b1[n];
            for (int s = 0; s < KSIZ; ++s) {
                float a0 = w1[(0*KSIZ + s)*32 + n];
                float a1 = w1[(1*KSIZ + s)*32 + n];
                float a2 = w1[(2*KSIZ + s)*32 + n];
                s0 += a0; s1 += a1; s2 += a2;
                bf -= centers[0*KSIZ+s]*a0 + centers[1*KSIZ+s]*a1 + centers[2*KSIZ+s]*a2;
            }
            ws[0*32+n] = s0; ws[1*32+n] = s1; ws[2*32+n] = s2; ws[96+n] = bf;
        }
        return;
    }
    const int kk = b >> 2, nt = b & 3;
    const int l  = tid, li = l & 15, g = l >> 4;
    unsigned short u[8];
    #pragma unroll
    for (int e = 0; e < 8; ++e) {
        int s = kk*32 + g*8 + e;
        int j = s >> 6;
        int c = s & 63;
        union { _Float16 h; unsigned short s16; } cv;
        cv.h = (_Float16)weight[(c*16 + j)*64 + nt*16 + li];
        u[e] = cv.s16;
    }
    uint4 v;
    v.x = u[0] | ((unsigned)u[1] << 16);
    v.y = u[2] | ((unsigned)u[3] << 16);
    v.z = u[4] | ((unsigned)u[5] << 16);
    v.w = u[6] | ((unsigned)u[7] << 16);
    wf[(kk*4 + nt)*64 + l] = v;
}

__global__ __launch_bounds__(256, 4)
void ptconv_kernel(const float* __restrict__ features,
                   const float* __restrict__ input_pts,
                   const float* __restrict__ output_pts,
                   const float* __restrict__ bias,
                   const float* __restrict__ w2,
                   const float* __restrict__ b2,
                   const float* __restrict__ w3,
                   const float* __restrict__ b3,
                   const int*   __restrict__ indices,
                   const float* __restrict__ folded,
                   const uint4* __restrict__ wf,
                   float* __restrict__ out) {
    // LDS (34560 B -> 4 blocks/CU):
    //   [0, 33024)      s_agg [16 pts][2064B]  rows [j=0..15][c=0..63] f16 + 16B pad
    //                   aliased by s_h1 [256 rows][80B] during layers 1-2
    //   [33024, 34048)  s_idx [256] int
    //   [34048, 34560)  s_par [128] float
    __shared__ __align__(16) char smem[34560];
    char*  s_agg = smem;
    char*  s_h1  = smem;
    int*   s_idx = (int*)(smem + 33024);
    float* s_par = (float*)(smem + 34048);

    const int t    = threadIdx.x;
    const int l    = t & 63;
    const int wave = t >> 6;
    const int li   = l & 15;
    const int g    = l >> 4;
    const int m0   = blockIdx.x * PTS;
    const int bbk  = m0 >> 14;

    if (t < 128) s_par[t] = folded[t];

    // per-thread neighbor (point p1, neighbor k1)
    const int p1 = t >> 4, k1 = t & 15;
    const int nn = (m0 + p1) & (NPTS-1);
    const int idxv = indices[(bbk*NPTS + nn)*KN + k1];
    s_idx[p1*16 + k1] = idxv;
    const float* ip = input_pts  + (size_t)(bbk*NPTS + idxv)*3;
    const float* op = output_pts + (size_t)(bbk*NPTS + nn)*3;
    const float r0 = ip[0]-op[0], r1 = ip[1]-op[1], r2 = ip[2]-op[2];

    // weight fragments / biases in registers (one-time)
    h8v w2f; h4v w3f;
    #pragma unroll
    for (int e = 0; e < 8; ++e) w2f[e] = (_Float16)w2[(8*g+e)*16 + li];
    #pragma unroll
    for (int e = 0; e < 4; ++e) w3f[e] = (_Float16)w3[(4*g+e)*16 + li];
    const f32x4 b2v4  = *(const f32x4*)(b2 + 4*g);   // bias per unit row 4g+r
    const float b3v   = b3[li];                      // bias per j col li
    const float biasO = bias[wave*16 + li];

    __syncthreads();                                 // s_par staged

    // ---- layer 1 (VALU, affine-folded): h1 -> s_h1[row t] (f16 pairs) ----
    {
        const float4* W0 = (const float4*)(s_par + 0);
        const float4* W1 = (const float4*)(s_par + 32);
        const float4* W2 = (const float4*)(s_par + 64);
        const float4* BF = (const float4*)(s_par + 96);
        unsigned o16[16];
        #pragma unroll
        for (int q = 0; q < 8; ++q) {
            const float4 bq = BF[q], a0 = W0[q], a1 = W1[q], a2 = W2[q];
            float v0 = fmaxf(fmaf(r2, a2.x, fmaf(r1, a1.x, fmaf(r0, a0.x, bq.x))), 0.f);
            float v1 = fmaxf(fmaf(r2, a2.y, fmaf(r1, a1.y, fmaf(r0, a0.y, bq.y))), 0.f);
            float v2 = fmaxf(fmaf(r2, a2.z, fmaf(r1, a1.z, fmaf(r0, a0.z, bq.z))), 0.f);
            float v3 = fmaxf(fmaf(r2, a2.w, fmaf(r1, a1.w, fmaf(r0, a0.w, bq.w))), 0.f);
            H2U u0, u1;
            u0.h = __builtin_amdgcn_cvt_pkrtz(v0, v1);
            u1.h = __builtin_amdgcn_cvt_pkrtz(v2, v3);
            o16[2*q]   = u0.u;
            o16[2*q+1] = u1.u;
        }
        uint4* dst = (uint4*)(s_h1 + t*80);
        dst[0] = make_uint4(o16[0],  o16[1],  o16[2],  o16[3]);
        dst[1] = make_uint4(o16[4],  o16[5],  o16[6],  o16[7]);
        dst[2] = make_uint4(o16[8],  o16[9],  o16[10], o16[11]);
        dst[3] = make_uint4(o16[12], o16[13], o16[14], o16[15]);
    }

    // ---- issue feature gathers early (overlap with MFMA layers below) ----
    // B-layout choice: tile ct covers c = 4*n + ct -> lane (g,li) needs
    // feat[idx[4g+e]][4li..4li+3] = one float4 per e.
    const float* fb = features + (size_t)bbk*NPTS*CIN;
    f32x4 rv[4][4];
    #pragma unroll
    for (int pp = 0; pp < 4; ++pp) {
        const int p2 = wave*4 + pp;
        const int4 id4 = *(const int4*)(s_idx + p2*16 + 4*g);   // broadcast (within-wave data)
        rv[pp][0] = *(const f32x4*)(fb + (size_t)id4.x*CIN + 4*li);
        rv[pp][1] = *(const f32x4*)(fb + (size_t)id4.y*CIN + 4*li);
        rv[pp][2] = *(const f32x4*)(fb + (size_t)id4.z*CIN + 4*li);
        rv[pp][3] = *(const f32x4*)(fb + (size_t)id4.w*CIN + 4*li);
    }

    // ---- layers 2+3 on MFMA, register-chained (no LDS between) ----
    // L2 swapped: D2[m=unit][n=nbr] = mfma(A=w2^T, B=h1^T). B from s_h1 (own wave's rows).
    // L3:         D3[m=nbr][n=j]    = mfma(A=relu(D2) in-lane, B=w3).
    // dreg[pp]  = relu(D3) in-lane = phase-2 A-fragment.
    h4v dreg[4];
    #pragma unroll
    for (int pp = 0; pp < 4; ++pp) {
        const int mt = wave*4 + pp;
        h8v B2 = *(const h8v*)(s_h1 + (mt*16 + li)*80 + g*16);  // h1[nbr=li][i=8g+e]
        f32x4 acc2 = b2v4;
        acc2 = __builtin_amdgcn_mfma_f32_16x16x32_f16(w2f, B2, acc2, 0, 0, 0);
        H4U A3;
        A3.p[0] = __builtin_amdgcn_cvt_pkrtz(fmaxf(acc2[0],0.f), fmaxf(acc2[1],0.f));
        A3.p[1] = __builtin_amdgcn_cvt_pkrtz(fmaxf(acc2[2],0.f), fmaxf(acc2[3],0.f));
        f32x4 acc3 = {b3v, b3v, b3v, b3v};
        acc3 = __builtin_amdgcn_mfma_f32_16x16x16f16(A3.v, w3f, acc3, 0, 0, 0);
        H4U Dv;
        Dv.p[0] = __builtin_amdgcn_cvt_pkrtz(fmaxf(acc3[0],0.f), fmaxf(acc3[1],0.f));
        Dv.p[1] = __builtin_amdgcn_cvt_pkrtz(fmaxf(acc3[2],0.f), fmaxf(acc3[3],0.f));
        dreg[pp] = Dv.v;
    }
    __syncthreads();   // all s_h1 reads done -> s_agg (alias) may be written

    // ---- phase 2: agg[m=j][n->c=4n+ct] = mfma(A=dreg, B=feat-gather), K=16 ----
    #pragma unroll
    for (int pp = 0; pp < 4; ++pp) {
        const int p2 = wave*4 + pp;
        f32x4 pacc[4];
        #pragma unroll
        for (int ct = 0; ct < 4; ++ct) {
            H4U B;
            B.p[0] = __builtin_amdgcn_cvt_pkrtz(rv[pp][0][ct], rv[pp][1][ct]);
            B.p[1] = __builtin_amdgcn_cvt_pkrtz(rv[pp][2][ct], rv[pp][3][ct]);
            f32x4 z = {0.f, 0.f, 0.f, 0.f};
            pacc[ct] = __builtin_amdgcn_mfma_f32_16x16x16f16(dreg[pp], B.v, z, 0, 0, 0);
        }
        // lane holds agg[j=4g+r][c=4li+ct]; row-major [j][c] f16 -> uint2 per r
        #pragma unroll
        for (int r = 0; r < 4; ++r) {
            H2U d01, d23;
            d01.h = __builtin_amdgcn_cvt_pkrtz(pacc[0][r], pacc[1][r]);  // c=4li,4li+1
            d23.h = __builtin_amdgcn_cvt_pkrtz(pacc[2][r], pacc[3][r]);  // c=4li+2,+3
            *(uint2*)(s_agg + p2*2064 + (4*g + r)*128 + 8*li) = make_uint2(d01.u, d23.u);
        }
    }
    __syncthreads();

    // ---- phase 3: out[16 pts][64] = AGG[16][1024] x W[1024][64], n-tile = wave ----
    f32x4 acc = {0.f, 0.f, 0.f, 0.f};
    #pragma unroll 4
    for (int kk = 0; kk < 32; ++kk) {
        h8v Bf = *(const h8v*)&wf[(kk*4 + wave)*64 + l];          // 16B coalesced (L2)
        h8v Af = *(const h8v*)(s_agg + li*2064 + kk*64 + g*16);   // point li, slots kk*32+8g+e
        acc = __builtin_amdgcn_mfma_f32_16x16x32_f16(Af, Bf, acc, 0, 0, 0);
    }
    #pragma unroll
    for (int r = 0; r < 4; ++r) {
        const int mr = g*4 + r;
        out[(size_t)(m0 + mr)*COUT + wave*16 + li] = acc[r]*0.0625f + biasO;
    }
}

extern "C" void kernel_launch(void* const* d_in, const int* in_sizes, int n_in,
                              void* d_out, int out_size, void* d_ws, size_t ws_size,
                              hipStream_t stream) {
    const float* features   = (const float*)d_in[0];
    const float* input_pts  = (const float*)d_in[1];
    const float* output_pts = (const float*)d_in[2];
    const float* weight     = (const float*)d_in[3];
    const float* bias       = (const float*)d_in[4];
    const float* centers    = (const float*)d_in[5];
    const float* w1         = (const float*)d_in[6];
    const float* b1         = (const float*)d_in[7];
    const float* w2         = (const float*)d_in[8];
    const float* b2         = (const float*)d_in[9];
    const float* w3         = (const float*)d_in[10];
    const float* b3         = (const float*)d_in[11];
    const int*   indices    = (const int*)d_in[12];
    float* out = (float*)d_out;
    float* ws  = (float*)d_ws;
    uint4* wf  = (uint4*)((char*)d_ws + 512);   // 128 KB of f16 W fragments

    prep_kernel<<<129, 64, 0, stream>>>(weight, w1, b1, centers, ws, wf);

    const int total_pts = 4 * NPTS;             // 65536
    ptconv_kernel<<<total_pts / PTS, 256, 0, stream>>>(
        features, input_pts, output_pts, bias,
        w2, b2, w3, b3, indices, ws, wf, out);
}

// Round 7
// 50.149 us; speedup vs baseline: 5.6316x; 1.0427x over previous
//
#include <hip/hip_runtime.h>

#define NPTS 16384
#define KN   16
#define CIN  64
#define COUT 64
#define KSIZ 16
#define PTS  16      // points per block

typedef _Float16 h4v    __attribute__((ext_vector_type(4)));
typedef _Float16 h8v    __attribute__((ext_vector_type(8)));
typedef __fp16   fp16x2 __attribute__((ext_vector_type(2)));
typedef float    f32x4  __attribute__((ext_vector_type(4)));

union H2U { fp16x2 h; unsigned u; };
union H4U { h4v v; fp16x2 p[2]; };
union H8U { h8v v; uint4 u4; };

// prep: blocks 0..127 pack W*(1/16) into f16 B-fragment order; block 128 folds
// layer-1 (affine in rel) and stores packed-f16 pairs:
//   ws dwords [0..16) W0p, [16..32) W1p, [32..48) W2p, [48..64) BFp
__global__ void prep_kernel(const float* __restrict__ weight,
                            const float* __restrict__ w1,
                            const float* __restrict__ b1,
                            const float* __restrict__ centers,
                            unsigned* __restrict__ wsp,
                            uint4* __restrict__ wf) {
    const int b = blockIdx.x;
    const int tid = threadIdx.x;
    if (b == 128) {
        __shared__ float tmp[4][32];
        if (tid < 32) {
            int n = tid;
            float s0 = 0.f, s1 = 0.f, s2 = 0.f, bf = b1[n];
            for (int s = 0; s < KSIZ; ++s) {
                float a0 = w1[(0*KSIZ + s)*32 + n];
                float a1 = w1[(1*KSIZ + s)*32 + n];
                float a2 = w1[(2*KSIZ + s)*32 + n];
                s0 += a0; s1 += a1; s2 += a2;
                bf -= centers[0*KSIZ+s]*a0 + centers[1*KSIZ+s]*a1 + centers[2*KSIZ+s]*a2;
            }
            tmp[0][n] = s0; tmp[1][n] = s1; tmp[2][n] = s2; tmp[3][n] = bf;
        }
        __syncthreads();
        if (tid < 64) {
            const int row = tid >> 4, q = tid & 15;
            union { _Float16 h[2]; unsigned u; } pk;
            pk.h[0] = (_Float16)tmp[row][2*q];
            pk.h[1] = (_Float16)tmp[row][2*q+1];
            wsp[row*16 + q] = pk.u;
        }
        return;
    }
    // W fragments: slot s (0..1023) <-> (j,c): j = s>>6, c = s&63.
    // Fragment: K-step kk, n-tile nt, lane l, elem e -> s = kk*32 + (l>>4)*8 + e,
    //           o = nt*16 + (l&15). Consumer uses identical maps -> k-perm-invariant.
    const int kk = b >> 2, nt = b & 3;
    const int l  = tid, li = l & 15, g = l >> 4;
    unsigned short u[8];
    #pragma unroll
    for (int e = 0; e < 8; ++e) {
        int s = kk*32 + g*8 + e;
        int j = s >> 6;
        int c = s & 63;
        union { _Float16 h; unsigned short s16; } cv;
        cv.h = (_Float16)(weight[(c*16 + j)*64 + nt*16 + li] * 0.0625f);
        u[e] = cv.s16;
    }
    uint4 v;
    v.x = u[0] | ((unsigned)u[1] << 16);
    v.y = u[2] | ((unsigned)u[3] << 16);
    v.z = u[4] | ((unsigned)u[5] << 16);
    v.w = u[6] | ((unsigned)u[7] << 16);
    wf[(kk*4 + nt)*64 + l] = v;
}

__global__ __launch_bounds__(256, 4)
void ptconv_kernel(const float* __restrict__ features,
                   const float* __restrict__ input_pts,
                   const float* __restrict__ output_pts,
                   const float* __restrict__ bias,
                   const float* __restrict__ w2,
                   const float* __restrict__ b2,
                   const float* __restrict__ w3,
                   const float* __restrict__ b3,
                   const int*   __restrict__ indices,
                   const unsigned* __restrict__ folded,  // 64 packed-f16 dwords (uniform)
                   const uint4* __restrict__ wf,
                   float* __restrict__ out) {
    // LDS (34048 B -> 4 blocks/CU):
    //   [0, 33024)      s_agg [16 pts][2064B] rows [j][c] f16 + 16B pad.
    //                   Wave w's region [8256w, 8256(w+1)) ALSO holds its own h1
    //                   rows (lane*80B) during layers 1-2 -> alias is wave-private,
    //                   no barrier needed between h1 use and agg write.
    //   [33024, 34048)  s_idx [256] int (wave-private quarters)
    __shared__ __align__(16) char smem[34048];
    char* s_agg = smem;
    int*  s_idx = (int*)(smem + 33024);

    const int t    = threadIdx.x;
    const int l    = t & 63;
    const int wave = t >> 6;
    const int li   = l & 15;
    const int g    = l >> 4;
    const int m0   = blockIdx.x * PTS;
    const int bbk  = m0 >> 14;

    // per-thread neighbor (point p1, neighbor k1)
    const int p1 = t >> 4, k1 = t & 15;
    const int nn = (m0 + p1) & (NPTS-1);
    const int idxv = indices[(bbk*NPTS + nn)*KN + k1];
    s_idx[p1*16 + k1] = idxv;
    const float* ip = input_pts  + (size_t)(bbk*NPTS + idxv)*3;
    const float* op = output_pts + (size_t)(bbk*NPTS + nn)*3;
    const float r0 = ip[0]-op[0], r1 = ip[1]-op[1], r2 = ip[2]-op[2];

    // weight fragments / biases in registers (one-time)
    h8v w2f; h4v w3f;
    #pragma unroll
    for (int e = 0; e < 8; ++e) w2f[e] = (_Float16)w2[(8*g+e)*16 + li];
    #pragma unroll
    for (int e = 0; e < 4; ++e) w3f[e] = (_Float16)w3[(4*g+e)*16 + li];
    const f32x4 b2v4  = *(const f32x4*)(b2 + 4*g);
    const float b3v   = b3[li];
    const float biasO = bias[wave*16 + li];

    // ---- layer 1, packed f16 via native fp16x2 vector ops ----
    {
        const __fp16 r0h = (__fp16)r0, r1h = (__fp16)r1, r2h = (__fp16)r2;
        fp16x2 r0p = {r0h, r0h}, r1p = {r1h, r1h}, r2p = {r2h, r2h};
        const fp16x2 zz = {(__fp16)0.f, (__fp16)0.f};
        unsigned o16[16];
        #pragma unroll
        for (int q = 0; q < 16; ++q) {
            H2U a, u0, u1, u2;
            a.u  = folded[48+q];
            u0.u = folded[q];
            u1.u = folded[16+q];
            u2.u = folded[32+q];
            fp16x2 acc = r0p*u0.h + a.h;     // v_pk_fma_f16 (contract)
            acc = r1p*u1.h + acc;
            acc = r2p*u2.h + acc;
            acc = __builtin_elementwise_max(acc, zz);   // v_pk_max_f16
            H2U o; o.h = acc; o16[q] = o.u;
        }
        uint4* dst = (uint4*)(smem + wave*8256 + l*80);   // own-wave region
        dst[0] = make_uint4(o16[0],  o16[1],  o16[2],  o16[3]);
        dst[1] = make_uint4(o16[4],  o16[5],  o16[6],  o16[7]);
        dst[2] = make_uint4(o16[8],  o16[9],  o16[10], o16[11]);
        dst[3] = make_uint4(o16[12], o16[13], o16[14], o16[15]);
    }

    // ---- issue feature gathers early (overlap with MFMA layers) ----
    const float* fb = features + (size_t)bbk*NPTS*CIN;
    f32x4 rv[4][4];
    #pragma unroll
    for (int pp = 0; pp < 4; ++pp) {
        const int p2 = wave*4 + pp;
        const int4 id4 = *(const int4*)(s_idx + p2*16 + 4*g);  // wave-private
        rv[pp][0] = *(const f32x4*)(fb + (size_t)id4.x*CIN + 4*li);
        rv[pp][1] = *(const f32x4*)(fb + (size_t)id4.y*CIN + 4*li);
        rv[pp][2] = *(const f32x4*)(fb + (size_t)id4.z*CIN + 4*li);
        rv[pp][3] = *(const f32x4*)(fb + (size_t)id4.w*CIN + 4*li);
    }

    // ---- layers 2+3 on MFMA, register-chained ----
    h4v dreg[4];
    #pragma unroll
    for (int pp = 0; pp < 4; ++pp) {
        h8v B2 = *(const h8v*)(smem + wave*8256 + (pp*16 + li)*80 + g*16);
        f32x4 acc2 = b2v4;
        acc2 = __builtin_amdgcn_mfma_f32_16x16x32_f16(w2f, B2, acc2, 0, 0, 0);
        H4U A3;
        A3.p[0] = __builtin_amdgcn_cvt_pkrtz(fmaxf(acc2[0],0.f), fmaxf(acc2[1],0.f));
        A3.p[1] = __builtin_amdgcn_cvt_pkrtz(fmaxf(acc2[2],0.f), fmaxf(acc2[3],0.f));
        f32x4 acc3 = {b3v, b3v, b3v, b3v};
        acc3 = __builtin_amdgcn_mfma_f32_16x16x16f16(A3.v, w3f, acc3, 0, 0, 0);
        H4U Dv;
        Dv.p[0] = __builtin_amdgcn_cvt_pkrtz(fmaxf(acc3[0],0.f), fmaxf(acc3[1],0.f));
        Dv.p[1] = __builtin_amdgcn_cvt_pkrtz(fmaxf(acc3[2],0.f), fmaxf(acc3[3],0.f));
        dreg[pp] = Dv.v;
    }

    // ---- phase 2: agg[j][c] = mfma(dreg, gathered features), K=16 ----
    #pragma unroll
    for (int pp = 0; pp < 4; ++pp) {
        const int p2 = wave*4 + pp;
        f32x4 pacc[4];
        #pragma unroll
        for (int ct = 0; ct < 4; ++ct) {
            H4U B;
            B.p[0] = __builtin_amdgcn_cvt_pkrtz(rv[pp][0][ct], rv[pp][1][ct]);
            B.p[1] = __builtin_amdgcn_cvt_pkrtz(rv[pp][2][ct], rv[pp][3][ct]);
            f32x4 z = {0.f, 0.f, 0.f, 0.f};
            pacc[ct] = __builtin_amdgcn_mfma_f32_16x16x16f16(dreg[pp], B.v, z, 0, 0, 0);
        }
        #pragma unroll
        for (int r = 0; r < 4; ++r) {
            H2U d01, d23;
            d01.h = __builtin_amdgcn_cvt_pkrtz(pacc[0][r], pacc[1][r]);
            d23.h = __builtin_amdgcn_cvt_pkrtz(pacc[2][r], pacc[3][r]);
            *(uint2*)(s_agg + p2*2064 + (4*g + r)*128 + 8*li) = make_uint2(d01.u, d23.u);
        }
    }

    // ---- pre-load phase-3 wf batch A (kk 0..7): in flight across the barrier ----
    const uint4* wp = wf + wave*64 + l;      // + kk*256 per K-step
    uint4 wa0 = wp[0*256], wa1 = wp[1*256], wa2 = wp[2*256], wa3 = wp[3*256];
    uint4 wa4 = wp[4*256], wa5 = wp[5*256], wa6 = wp[6*256], wa7 = wp[7*256];

    __syncthreads();   // the ONLY barrier: agg transpose point->lane

    // ---- phase 3: out[16][64] = AGG[16][1024] x Wf[1024][64], n-tile = wave ----
    __builtin_amdgcn_s_setprio(1);
    f32x4 acc = {0.f, 0.f, 0.f, 0.f};
#define AREAD(KK) (*(const h8v*)(s_agg + li*2064 + (KK)*64 + g*16))
#define MF(KK, WREG) { H8U bu_; bu_.u4 = WREG; acc = __builtin_amdgcn_mfma_f32_16x16x32_f16(AREAD(KK), bu_.v, acc, 0, 0, 0); }
    uint4 wb0 = wp[ 8*256], wb1 = wp[ 9*256], wb2 = wp[10*256], wb3 = wp[11*256];
    uint4 wb4 = wp[12*256], wb5 = wp[13*256], wb6 = wp[14*256], wb7 = wp[15*256];
    MF(0, wa0) MF(1, wa1) MF(2, wa2) MF(3, wa3)
    MF(4, wa4) MF(5, wa5) MF(6, wa6) MF(7, wa7)
    uint4 wc0 = wp[16*256], wc1 = wp[17*256], wc2 = wp[18*256], wc3 = wp[19*256];
    uint4 wc4 = wp[20*256], wc5 = wp[21*256], wc6 = wp[22*256], wc7 = wp[23*256];
    MF( 8, wb0) MF( 9, wb1) MF(10, wb2) MF(11, wb3)
    MF(12, wb4) MF(13, wb5) MF(14, wb6) MF(15, wb7)
    uint4 wd0 = wp[24*256], wd1 = wp[25*256], wd2 = wp[26*256], wd3 = wp[27*256];
    uint4 wd4 = wp[28*256], wd5 = wp[29*256], wd6 = wp[30*256], wd7 = wp[31*256];
    MF(16, wc0) MF(17, wc1) MF(18, wc2) MF(19, wc3)
    MF(20, wc4) MF(21, wc5) MF(22, wc6) MF(23, wc7)
    MF(24, wd0) MF(25, wd1) MF(26, wd2) MF(27, wd3)
    MF(28, wd4) MF(29, wd5) MF(30, wd6) MF(31, wd7)
#undef MF
#undef AREAD
    __builtin_amdgcn_s_setprio(0);

    #pragma unroll
    for (int r = 0; r < 4; ++r) {
        const int mr = g*4 + r;
        out[(size_t)(m0 + mr)*COUT + wave*16 + li] = acc[r] + biasO;
    }
}

extern "C" void kernel_launch(void* const* d_in, const int* in_sizes, int n_in,
                              void* d_out, int out_size, void* d_ws, size_t ws_size,
                              hipStream_t stream) {
    const float* features   = (const float*)d_in[0];
    const float* input_pts  = (const float*)d_in[1];
    const float* output_pts = (const float*)d_in[2];
    const float* weight     = (const float*)d_in[3];
    const float* bias       = (const float*)d_in[4];
    const float* centers    = (const float*)d_in[5];
    const float* w1         = (const float*)d_in[6];
    const float* b1         = (const float*)d_in[7];
    const float* w2         = (const float*)d_in[8];
    const float* b2         = (const float*)d_in[9];
    const float* w3         = (const float*)d_in[10];
    const float* b3         = (const float*)d_in[11];
    const int*   indices    = (const int*)d_in[12];
    float* out = (float*)d_out;
    unsigned* wsp = (unsigned*)d_ws;
    uint4* wf = (uint4*)((char*)d_ws + 512);   // 128 KB of f16 W fragments

    prep_kernel<<<129, 64, 0, stream>>>(weight, w1, b1, centers, wsp, wf);

    const int total_pts = 4 * NPTS;            // 65536
    ptconv_kernel<<<total_pts / PTS, 256, 0, stream>>>(
        features, input_pts, output_pts, bias,
        w2, b2, w3, b3, indices, wsp, wf, out);
}